// Round 5
// baseline (1136.648 us; speedup 1.0000x reference)
//
#include <hip/hip_runtime.h>
#include <hip/hip_bf16.h>

#define NN 100000
#define NE 1250000
#define DD 64
#define RR 16
#define NKEY 1600000          // RR*NN
#define NTILEC 78125          // cap: ceil(NE/16) rows worst-case
#define NBLK_SCAN 391         // ceil(NN/256)
#define NBLK_KEY 6250         // NKEY/256

typedef __attribute__((ext_vector_type(8))) short s16x8;
typedef __attribute__((ext_vector_type(4))) float f32x4;

static __device__ __forceinline__ unsigned short f2bf(float v) {
    __hip_bfloat16 h = __float2bfloat16(v);
    return __builtin_bit_cast(unsigned short, h);
}
static __device__ __forceinline__ float bf2f(unsigned short u) {
    unsigned int w = ((unsigned int)u) << 16;
    return __builtin_bit_cast(float, w);
}
static __device__ __forceinline__ unsigned int pack2(float a, float b) {
    return ((unsigned int)f2bf(b) << 16) | (unsigned int)f2bf(a);
}

// ============ build compact (src,rel) row table ============

__global__ void flag_key(const int* __restrict__ src, const int* __restrict__ et,
                         unsigned char* __restrict__ flagK) {
    int e = blockIdx.x * 256 + threadIdx.x;
    if (e < NE) flagK[et[e] * NN + src[e]] = 1;   // benign races
}

__global__ __launch_bounds__(256) void scanA(const unsigned char* __restrict__ flagK,
                                             int* __restrict__ rowmap, int* __restrict__ partK) {
    __shared__ int s[256];
    int i = blockIdx.x * 256 + threadIdx.x;
    int v = flagK[i] ? 1 : 0;                    // grid covers NKEY exactly
    s[threadIdx.x] = v;
    __syncthreads();
    for (int off = 1; off < 256; off <<= 1) {
        int t = (threadIdx.x >= off) ? s[threadIdx.x - off] : 0;
        __syncthreads();
        s[threadIdx.x] += t;
        __syncthreads();
    }
    rowmap[i] = s[threadIdx.x] - v;              // exclusive within block
    if (threadIdx.x == 255) partK[blockIdx.x] = s[255];
}

__global__ __launch_bounds__(1024) void scanB(int* __restrict__ partK) {
    __shared__ int s[1024];
    int t = threadIdx.x;
    int b0 = t * 7, b1 = min(b0 + 7, NBLK_KEY);
    int loc[7];
    int sum = 0;
    for (int j = b0; j < b1; ++j) { loc[j - b0] = partK[j]; sum += loc[j - b0]; }
    s[t] = sum;
    __syncthreads();
    for (int off = 1; off < 1024; off <<= 1) {
        int v = (t >= off) ? s[t - off] : 0;
        __syncthreads();
        s[t] += v;
        __syncthreads();
    }
    int excl = s[t] - sum;
    for (int j = b0; j < b1; ++j) { int v = loc[j - b0]; partK[j] = excl; excl += v; }
}

__global__ void scanC_emit(const unsigned char* __restrict__ flagK, int* __restrict__ rowmap,
                           const int* __restrict__ partK,
                           int* __restrict__ rsrc, int* __restrict__ rrel) {
    int i = blockIdx.x * 256 + threadIdx.x;     // grid covers NKEY exactly
    int rid = rowmap[i] + partK[blockIdx.x];
    rowmap[i] = rid;
    if (flagK[i]) {
        int rel = i / NN;                        // constant-div -> magic mul
        rsrc[rid] = i - rel * NN;
        rrel[rid] = rel;
    }
}

// ============ sort edges by dst (counting sort, NN bins) ============

__global__ void hist_dst(const int* __restrict__ dst, int* __restrict__ cnt) {
    int e = blockIdx.x * 256 + threadIdx.x;
    if (e < NE) atomicAdd(&cnt[dst[e]], 1);
}

__global__ __launch_bounds__(256) void scan1(const int* __restrict__ cnt,
                                             int* __restrict__ rp, int* __restrict__ part) {
    __shared__ int s[256];
    int i = blockIdx.x * 256 + threadIdx.x;
    int v = (i < NN) ? cnt[i] : 0;
    s[threadIdx.x] = v;
    __syncthreads();
    for (int off = 1; off < 256; off <<= 1) {
        int t = (threadIdx.x >= off) ? s[threadIdx.x - off] : 0;
        __syncthreads();
        s[threadIdx.x] += t;
        __syncthreads();
    }
    if (i < NN) rp[i] = s[threadIdx.x] - v;
    if (threadIdx.x == 255) part[blockIdx.x] = s[255];
}

__global__ void scan2(int* __restrict__ part) {
    __shared__ int s[NBLK_SCAN];
    if (threadIdx.x < NBLK_SCAN) s[threadIdx.x] = part[threadIdx.x];
    __syncthreads();
    if (threadIdx.x == 0) {
        int acc = 0;
        for (int b = 0; b < NBLK_SCAN; ++b) { int t = s[b]; s[b] = acc; acc += t; }
    }
    __syncthreads();
    if (threadIdx.x < NBLK_SCAN) part[threadIdx.x] = s[threadIdx.x];
}

__global__ void scan3(int* __restrict__ rp, const int* __restrict__ part, int* __restrict__ cur) {
    int i = blockIdx.x * 256 + threadIdx.x;
    if (i < NN) {
        int v = rp[i] + part[blockIdx.x];
        rp[i] = v;
        cur[i] = v;
    }
}

// scatter: sgd[p] = {compact row, dst}  (single 8B store per edge)
__global__ void scatter2(const int* __restrict__ src, const int* __restrict__ dst,
                         const int* __restrict__ et, const int* __restrict__ rowmap,
                         int* __restrict__ cur, int2* __restrict__ sgd) {
    int e = blockIdx.x * 256 + threadIdx.x;
    if (e >= NE) return;
    int d = dst[e];
    int row = rowmap[et[e] * NN + src[e]];
    int p = atomicAdd(&cur[d], 1);
    sgd[p] = make_int2(row, d);
}

// ============ precision prep ============

// wt[l][r][o][d] = bf16(W_l[r][d][o])
__global__ void prep_w(const float* __restrict__ W1, const float* __restrict__ W2,
                       unsigned short* __restrict__ wt) {
    int i = blockIdx.x * 256 + threadIdx.x;
    if (i >= 2 * RR * DD * DD) return;
    int d = i & 63;
    int o = (i >> 6) & 63;
    int r = (i >> 12) & 15;
    int l = i >> 16;
    const float* W = l ? W2 : W1;
    wt[i] = f2bf(W[(r * DD + d) * DD + o]);
}

// swT[l][o][d] = sw_l[d][o]  (fp32, transposed for the self kernels)
__global__ void prep_swT(const float* __restrict__ sw1, const float* __restrict__ sw2,
                         float* __restrict__ swT) {
    int i = blockIdx.x * 256 + threadIdx.x;
    if (i >= 2 * DD * DD) return;
    int d = i & 63;
    int o = (i >> 6) & 63;
    int l = i >> 12;
    swT[i] = (l ? sw2 : sw1)[d * DD + o];
}

__global__ void prep_x2(const float* __restrict__ x, unsigned short* __restrict__ xb) {
    int i = blockIdx.x * blockDim.x + threadIdx.x;
    if (i < NN * DD) xb[i] = f2bf(x[i]);
}

// ============ per-layer kernels ============

// compact transform: tabc[row][o] = x[rsrc[row]] @ W_{rrel[row]}  (bf16)
__global__ __launch_bounds__(256) void xw_c(
    const unsigned short* __restrict__ xb,   // [N][64] bf16 input features
    const unsigned short* __restrict__ wt,   // [16][64][64] bf16 (o-major, d inner), this layer
    const int* __restrict__ rsrc,            // [rowcap] src per compact row (0 for pads)
    const int* __restrict__ rrel,            // [rowcap] rel per compact row (0x3f3f3f3f for pads)
    unsigned short* __restrict__ tabc)       // [rowcap][64] bf16
{
    const int wid  = threadIdx.x >> 6;
    const int lane = threadIdx.x & 63;
    const int c = lane & 15;       // row within tile (C col)
    const int q = lane >> 4;
    const int tile = blockIdx.x * 4 + wid;
    if (tile >= NTILEC) return;
    const int row0 = tile * 16;

    const int myrel = rrel[row0 + c];
    const int r_lo = __shfl(myrel, 0, 64);
    if (r_lo > 15) return;                       // fully-pad tile
    const int r_hi = min(__shfl(myrel, 15, 64), 15);

    const int srcn = rsrc[row0 + c];
    const unsigned short* xrow = xb + (size_t)srcn * DD + q * 8;
    s16x8 b0 = *(const s16x8*)(xrow);
    s16x8 b1 = *(const s16x8*)(xrow + 32);

    uint2* orow = (uint2*)(tabc + (size_t)(row0 + c) * DD);

    for (int r = r_lo; r <= r_hi; ++r) {         // almost always 1 iteration
        const unsigned short* wp = wt + r * (DD * DD);
        const bool mine = (myrel == r);
        #pragma unroll
        for (int nb = 0; nb < 4; ++nb) {
            const unsigned short* wrow = wp + (nb * 16 + c) * DD + q * 8;
            s16x8 a0 = *(const s16x8*)(wrow);
            s16x8 a1 = *(const s16x8*)(wrow + 32);
            f32x4 acc = {0.f, 0.f, 0.f, 0.f};
            acc = __builtin_amdgcn_mfma_f32_16x16x32_bf16(a0, b0, acc, 0, 0, 0);
            acc = __builtin_amdgcn_mfma_f32_16x16x32_bf16(a1, b1, acc, 0, 0, 0);
            if (mine) {
                uint2 pk;
                pk.x = pack2(acc[0], acc[1]);
                pk.y = pack2(acc[2], acc[3]);
                orow[nb * 4 + q] = pk;           // o = nb*16 + q*4
            }
        }
    }
}

// self transform init: carry[n][o] = bias[o] + h[n]·swT[o] (+ x[n][o] res)
__global__ __launch_bounds__(256) void self_f32(
    const float* __restrict__ h, const float* __restrict__ swT,
    const float* __restrict__ bias, const float* __restrict__ xres,
    float* __restrict__ carry)
{
    int idx = blockIdx.x * 256 + threadIdx.x;
    if (idx >= NN * DD) return;
    int o = idx & 63;
    int n = idx >> 6;
    const float4* xrow = (const float4*)(h + (size_t)n * DD);
    const float4* srow = (const float4*)(swT + o * DD);
    float acc = bias[o];
    if (xres) acc += xres[idx];
    #pragma unroll
    for (int j = 0; j < 16; ++j) {
        float4 a = xrow[j], w = srow[j];
        acc += a.x * w.x + a.y * w.y + a.z * w.z + a.w * w.w;
    }
    carry[idx] = acc;
}

__global__ __launch_bounds__(256) void self_bf(
    const unsigned short* __restrict__ hb, const float* __restrict__ swT,
    const float* __restrict__ bias, float* __restrict__ carry)
{
    int idx = blockIdx.x * 256 + threadIdx.x;
    if (idx >= NN * DD) return;
    int o = idx & 63;
    int n = idx >> 6;
    const unsigned int* hrow = (const unsigned int*)(hb + (size_t)n * DD);
    const float2* srow = (const float2*)(swT + o * DD);
    float acc = bias[o];
    #pragma unroll
    for (int j = 0; j < 32; ++j) {
        unsigned int u = hrow[j];
        float2 w = srow[j];
        acc += bf2f((unsigned short)u) * w.x + bf2f((unsigned short)(u >> 16)) * w.y;
    }
    carry[idx] = acc;
}

// chunked gather-accumulate: each wave owns 64 consecutive dst-sorted edges,
// issues 8 independent gathers per batch, flushes on dst change via HW atomics.
#define CHUNK 64
__global__ __launch_bounds__(256) void agg_kernel(
    const unsigned int* __restrict__ tab32,  // tabc viewed as uint [row][32]
    const int2* __restrict__ sgd,            // [E] {row, dst}
    float* __restrict__ carry)               // [N][64] fp32 (pre-initialized)
{
    const int wid  = threadIdx.x >> 6;
    const int lane = threadIdx.x & 63;
    const int h  = lane >> 5;                // half-wave: even/odd edge stream
    const int ol = lane & 31;                // channel pair: o = 2*ol, 2*ol+1
    const int e0 = (blockIdx.x * 4 + wid) * CHUNK;
    if (e0 >= NE) return;

    float a0 = 0.f, a1 = 0.f;
    int cur = -1;
    for (int base = 0; base < CHUNK; base += 16) {   // 8 edges per half per batch
        int rowk[8], dk[8];
        unsigned int uk[8];
        #pragma unroll
        for (int j = 0; j < 8; ++j) {
            int e = e0 + base + 2 * j + h;
            if (e < NE) { int2 g = sgd[e]; rowk[j] = g.x; dk[j] = g.y; }
            else dk[j] = -1;
        }
        #pragma unroll
        for (int j = 0; j < 8; ++j)
            if (dk[j] >= 0) uk[j] = tab32[(size_t)rowk[j] * 32 + ol];
        #pragma unroll
        for (int j = 0; j < 8; ++j) {
            if (dk[j] < 0) continue;
            if (dk[j] != cur) {
                if (cur >= 0) {
                    unsafeAtomicAdd(&carry[(size_t)cur * DD + ol * 2],     a0);
                    unsafeAtomicAdd(&carry[(size_t)cur * DD + ol * 2 + 1], a1);
                }
                a0 = 0.f; a1 = 0.f;
                cur = dk[j];
            }
            a0 += bf2f((unsigned short)uk[j]);
            a1 += bf2f((unsigned short)(uk[j] >> 16));
        }
    }
    if (cur >= 0) {
        unsafeAtomicAdd(&carry[(size_t)cur * DD + ol * 2],     a0);
        unsafeAtomicAdd(&carry[(size_t)cur * DD + ol * 2 + 1], a1);
    }
}

// relu + emit (bf16 for next layer, or fp32 final output)
__global__ void fin_kernel(const float* __restrict__ carry,
                           unsigned short* __restrict__ outb, float* __restrict__ outf) {
    int i = blockIdx.x * 256 + threadIdx.x;
    if (i >= NN * DD) return;
    float v = fmaxf(carry[i], 0.f);
    if (outb) outb[i] = f2bf(v);
    if (outf) outf[i] = v;
}

// ================= launch =================

extern "C" void kernel_launch(void* const* d_in, const int* in_sizes, int n_in,
                              void* d_out, int out_size, void* d_ws, size_t ws_size,
                              hipStream_t stream)
{
    (void)in_sizes; (void)n_in; (void)out_size; (void)ws_size;
    const float* x    = (const float*)d_in[0];
    const int*   ei   = (const int*)d_in[1];
    const int*   et   = (const int*)d_in[2];
    const float* W1   = (const float*)d_in[3];
    const float* sw1  = (const float*)d_in[4];
    const float* b1   = (const float*)d_in[5];
    const float* W2   = (const float*)d_in[6];
    const float* sw2  = (const float*)d_in[7];
    const float* b2   = (const float*)d_in[8];
    float* out = (float*)d_out;

    const int* srcA = ei;
    const int* dstA = ei + NE;

    char* ws = (char*)d_ws;
    unsigned short* tabc  = (unsigned short*)(ws);                  // 160,000,000
    unsigned short* xb    = (unsigned short*)(ws + 160000000);      //  12,800,000
    unsigned short* h1b   = (unsigned short*)(ws + 172800000);      //  12,800,000
    float*          carry = (float*)(ws + 185600000);               //  25,600,000
    unsigned short* wt2   = (unsigned short*)(ws + 211200000);      //     262,144
    float*          swT   = (float*)(ws + 211462144);               //      32,768
    int2*           sgd   = (int2*)(ws + 211494912);                //  10,000,000
    int*            rowmap= (int*)(ws + 221494912);                 //   6,400,000
    unsigned char*  flagK = (unsigned char*)(ws + 227894912);       //   1,600,000
    int*            rsrc  = (int*)(ws + 229494912);                 //   5,004,096
    int*            rrel  = (int*)(ws + 234499008);                 //   5,004,096
    int*            cnt   = (int*)(ws + 239503104);                 //     400,000
    int*            rp    = (int*)(ws + 239903104);                 //     400,016
    int*            cur   = (int*)(ws + 240303120);                 //     400,000
    int*            partD = (int*)(ws + 240703120);                 //       1,600
    int*            partK = (int*)(ws + 240704720);                 //      25,000

    const int NB_E    = (NE + 255) / 256;        // 4883
    const int NB_ELEM = (NN * DD + 255) / 256;   // 25000
    const int NB_XWC  = (NTILEC + 3) / 4;        // 19532
    const int NB_AGG  = (NE + 4 * CHUNK - 1) / (4 * CHUNK);  // 4883

    // ---- build compact row table (once) ----
    hipMemsetAsync(flagK, 0, 1600000, stream);
    hipMemsetAsync(rsrc, 0, 5004096, stream);
    hipMemsetAsync(rrel, 0x3f, 5004096, stream);
    flag_key<<<NB_E, 256, 0, stream>>>(srcA, et, flagK);
    scanA<<<NBLK_KEY, 256, 0, stream>>>(flagK, rowmap, partK);
    scanB<<<1, 1024, 0, stream>>>(partK);
    scanC_emit<<<NBLK_KEY, 256, 0, stream>>>(flagK, rowmap, partK, rsrc, rrel);

    // ---- sort edges by dst (once) ----
    hipMemsetAsync(cnt, 0, NN * sizeof(int), stream);
    hist_dst<<<NB_E, 256, 0, stream>>>(dstA, cnt);
    scan1<<<NBLK_SCAN, 256, 0, stream>>>(cnt, rp, partD);
    scan2<<<1, 512, 0, stream>>>(partD);
    scan3<<<NBLK_SCAN, 256, 0, stream>>>(rp, partD, cur);
    scatter2<<<NB_E, 256, 0, stream>>>(srcA, dstA, et, rowmap, cur, sgd);

    // ---- precision prep ----
    prep_w<<<(2 * RR * DD * DD + 255) / 256, 256, 0, stream>>>(W1, W2, wt2);
    prep_swT<<<(2 * DD * DD + 255) / 256, 256, 0, stream>>>(sw1, sw2, swT);
    prep_x2<<<NB_ELEM, 256, 0, stream>>>(x, xb);

    // ---- layer 1 (residual) ----
    self_f32<<<NB_ELEM, 256, 0, stream>>>(x, swT, b1, x, carry);
    xw_c<<<NB_XWC, 256, 0, stream>>>(xb, wt2, rsrc, rrel, tabc);
    agg_kernel<<<NB_AGG, 256, 0, stream>>>((const unsigned int*)tabc, sgd, carry);
    fin_kernel<<<NB_ELEM, 256, 0, stream>>>(carry, h1b, nullptr);

    // ---- layer 2 (no residual) ----
    self_bf<<<NB_ELEM, 256, 0, stream>>>(h1b, swT + DD * DD, b2, carry);
    xw_c<<<NB_XWC, 256, 0, stream>>>(h1b, wt2 + RR * DD * DD, rsrc, rrel, tabc);
    agg_kernel<<<NB_AGG, 256, 0, stream>>>((const unsigned int*)tabc, sgd, carry);
    fin_kernel<<<NB_ELEM, 256, 0, stream>>>(carry, nullptr, out);
}